// Round 5
// baseline (2249.256 us; speedup 1.0000x reference)
//
#include <hip/hip_runtime.h>

// (B, N, D, H) = (8, 4096, 256, 8), PS=8 -> image 64x64, blocked M=64 (fine pos), N=64 (tile idx).
// KEY SPEC FACT 1: no softmax temperature; logit sigma ~16 => softmax ~= argmax => score chain
//   (a -> Q,K -> logits) must be fp32. Post-softmax paths can be bf16.
// KEY SPEC FACT 2: Z = einsum('bhmnd,hdv->bmnd', O, o) keeps d (diagonal) and SUMS v:
//   Z[b,m,n,d] = sum_h O[b,h,m,n,d] * os[h][d],  os[h][d] = sum_v o[h,d,v].  NOT a matmul over d.
#define Bc   8
#define Tc   4096
#define Dc   256
#define EPSc 1e-5f

typedef unsigned short ushort_t;

__device__ __forceinline__ ushort_t f2bf(float f){
  union{float f; unsigned u;} c; c.f = f;
  unsigned u = c.u;
  return (ushort_t)((u + 0x7fffu + ((u >> 16) & 1u)) >> 16);
}
__device__ __forceinline__ float bf2f(ushort_t h){ union{unsigned x; float f;} c; c.x = ((unsigned)h) << 16; return c.f; }
__device__ __forceinline__ float bf_lo(unsigned u){ union{unsigned x; float f;} c; c.x = u << 16; return c.f; }
__device__ __forceinline__ float bf_hi(unsigned u){ union{unsigned x; float f;} c; c.x = u & 0xffff0000u; return c.f; }

// ---------------- os[h][d] = sum_v o[h,d,v] ----------------
__global__ __launch_bounds__(256) void osum_kernel(const float* __restrict__ o, float* __restrict__ os) {
  int h = blockIdx.x, d = threadIdx.x;
  const float* row = o + ((size_t)h * 256 + d) * 256;
  float s = 0.f;
  #pragma unroll 8
  for (int v = 0; v < 256; v += 4) {
    float4 r4 = *(const float4*)&row[v];
    s += r4.x + r4.y + r4.z + r4.w;
  }
  os[h * 256 + d] = s;
}

// ---------------- LN1 + blocked permute, fp32 out ----------------
// a[b, m, n, d]: m=(h%8)*8+(w%8), n=(h/8)*8+(w/8)
__global__ __launch_bounds__(256) void ln1_kernel(
    const float* __restrict__ x, const float* __restrict__ w,
    const float* __restrict__ bia, float* __restrict__ aF) {
  int row = blockIdx.x;                 // b*4096 + p
  int d   = threadIdx.x;
  float v = x[(size_t)row * Dc + d];
  float s = v, sq = v * v;
  #pragma unroll
  for (int off = 32; off; off >>= 1) { s += __shfl_xor(s, off); sq += __shfl_xor(sq, off); }
  __shared__ float ps[4], pq[4];
  int wid = d >> 6, lane = d & 63;
  if (lane == 0) { ps[wid] = s; pq[wid] = sq; }
  __syncthreads();
  s  = ps[0] + ps[1] + ps[2] + ps[3];
  sq = pq[0] + pq[1] + pq[2] + pq[3];
  float mean = s * (1.f / Dc);
  float var  = sq * (1.f / Dc) - mean * mean;
  float r    = rsqrtf(var + EPSc);
  float y    = (v - mean) * r * w[d] + bia[d];
  int bb = row >> 12, p = row & 4095;
  int hh = p >> 6, ww = p & 63;
  int m = (hh & 7) * 8 + (ww & 7);
  int n = (hh >> 3) * 8 + (ww >> 3);
  aF[((size_t)((bb * 64 + m) * 64 + n)) * Dc + d] = y;
}

// ---------------- fp32-A matmul (32-row tile): K (fp32 out) / V (bf16 out) ----------------
__global__ __launch_bounds__(256) void mm_f32_kernel(
    const float* __restrict__ A, const float* __restrict__ W,
    float* outf, ushort_t* outb) {
  __shared__ __align__(16) float As[32 * 256];   // 32 KB
  int tid = threadIdx.x;
  int r0  = blockIdx.x * 32;
  for (int i = 0; i < 32; i++) As[i * 256 + tid] = A[(size_t)(r0 + i) * Dc + tid];
  __syncthreads();
  float acc[32];
  #pragma unroll
  for (int i = 0; i < 32; i++) acc[i] = 0.f;
  for (int d0 = 0; d0 < 256; d0 += 4) {
    float w0 = W[(d0 + 0) * 256 + tid];
    float w1 = W[(d0 + 1) * 256 + tid];
    float w2 = W[(d0 + 2) * 256 + tid];
    float w3 = W[(d0 + 3) * 256 + tid];
    #pragma unroll
    for (int i = 0; i < 32; i++) {
      float4 a4 = *(const float4*)&As[i * 256 + d0];   // broadcast read
      acc[i] += a4.x * w0 + a4.y * w1 + a4.z * w2 + a4.w * w3;
    }
  }
  #pragma unroll
  for (int i = 0; i < 32; i++) {
    size_t idx = (size_t)(r0 + i) * Dc + tid;
    if (outf) outf[idx] = acc[i];
    if (outb) outb[idx] = f2bf(acc[i]);
  }
}

// ---------------- bf16-A matmul (64-row tile): fc1 (relu) / fc2 (+resid) ----------------
__global__ __launch_bounds__(256) void mm_bf_kernel(
    const ushort_t* __restrict__ A, const float* __restrict__ W,
    const float* __restrict__ bias, const float* resid,
    ushort_t* outb, float* outf, int do_relu) {
  __shared__ __align__(16) ushort_t As[64 * 256];   // 32 KB
  int tid = threadIdx.x;
  int r0  = blockIdx.x * 64;
  for (int i = 0; i < 64; i++) As[i * 256 + tid] = A[(size_t)(r0 + i) * Dc + tid];
  __syncthreads();
  float acc[64];
  #pragma unroll
  for (int i = 0; i < 64; i++) acc[i] = 0.f;
  for (int d0 = 0; d0 < 256; d0 += 4) {
    float w0 = W[(d0 + 0) * 256 + tid];
    float w1 = W[(d0 + 1) * 256 + tid];
    float w2 = W[(d0 + 2) * 256 + tid];
    float w3 = W[(d0 + 3) * 256 + tid];
    #pragma unroll
    for (int i = 0; i < 64; i++) {
      uint2 a4 = *(const uint2*)&As[i * 256 + d0];
      acc[i] += bf_lo(a4.x) * w0 + bf_hi(a4.x) * w1 + bf_lo(a4.y) * w2 + bf_hi(a4.y) * w3;
    }
  }
  float bv = bias ? bias[tid] : 0.f;
  #pragma unroll
  for (int i = 0; i < 64; i++) {
    float v = acc[i] + bv;
    if (do_relu) v = fmaxf(v, 0.f);
    size_t idx = (size_t)(r0 + i) * Dc + tid;
    if (resid) v += resid[idx];
    if (outb) outb[idx] = f2bf(v);
    if (outf) outf[idx] = v;
  }
}

// ---------------- Fused attention, fp32 score chain, element-wise o-scale ----------------
// mode 0 (heads 0..3): fixed n=slice; queries/keys vary over m.  s1/O1 einsums.
// mode 1 (heads 4..7): fixed m=slice; queries/keys vary over n.  s2/O2 einsums.
// Z (token space, bf16) (+)= sum_heads (softmax(Q K^T) V) * os[h]
#define QR 16
__global__ __launch_bounds__(256) void attn_kernel(
    const float* __restrict__ aF, const float* __restrict__ Kg,
    const ushort_t* __restrict__ Vg, const float* __restrict__ q,
    const float* __restrict__ osum, ushort_t* Z, int mode) {
  __shared__ __align__(16) float shA[QR * 260];   // a-tile (phase A) / K-chunk (phase B)
  __shared__ __align__(16) float shQ[QR * 260];   // Q
  __shared__ __align__(16) float shS[QR * 68];    // softmax probs

  int tid = threadIdx.x;
  int idx = blockIdx.x;               // 2048 = 8b * 64 slices * 4 quarters
  int b = idx >> 8;
  int slice = (idx >> 2) & 63;
  int x0 = (idx & 3) * QR;

  float zacc[QR];
  #pragma unroll
  for (int i = 0; i < QR; i++) zacc[i] = 0.f;

  int hbase = mode ? 4 : 0;
  for (int hh = 0; hh < 4; hh++) {
    int h = hbase + hh;
    float os_h = osum[h * 256 + tid];             // Z[...,d=tid] scale for this head
    __syncthreads();                               // S1: prev head's shS readers / shA readers done
    // --- stage a query-tile (fp32) ---
    for (int i = 0; i < QR; i++) {
      size_t r = mode ? ((size_t)(b * 64 + slice) * 64 + x0 + i)
                      : ((size_t)(b * 64 + x0 + i) * 64 + slice);
      shA[i * 260 + tid] = aF[r * Dc + tid];
    }
    __syncthreads();                               // S2
    // --- phase A: Q = a @ q[h], col tid ---
    {
      float qacc[QR];
      #pragma unroll
      for (int i = 0; i < QR; i++) qacc[i] = 0.f;
      const float* qh = q + (size_t)h * 65536;
      for (int d0 = 0; d0 < 256; d0 += 4) {
        float w0 = qh[(d0 + 0) * 256 + tid];
        float w1 = qh[(d0 + 1) * 256 + tid];
        float w2 = qh[(d0 + 2) * 256 + tid];
        float w3 = qh[(d0 + 3) * 256 + tid];
        #pragma unroll
        for (int i = 0; i < QR; i++) {
          float4 a4 = *(const float4*)&shA[i * 260 + d0];
          qacc[i] += a4.x * w0 + a4.y * w1 + a4.z * w2 + a4.w * w3;
        }
      }
      #pragma unroll
      for (int i = 0; i < QR; i++) shQ[i * 260 + tid] = qacc[i];
    }
    __syncthreads();                               // S3: Q visible, shA free
    // --- phase B: fp32 scores, K in 16-row chunks ---
    int xq = tid >> 4;       // query row 0..15
    int zl = tid & 15;       // z within chunk
    float sc[4];
    #pragma unroll
    for (int zc = 0; zc < 4; zc++) sc[zc] = 0.f;
    for (int zc = 0; zc < 4; zc++) {
      if (zc > 0) __syncthreads();                 // prev chunk readers done
      for (int j = 0; j < 16; j++) {
        int z = zc * 16 + j;
        size_t r = mode ? ((size_t)(b * 64 + slice) * 64 + z)
                        : ((size_t)(b * 64 + z) * 64 + slice);
        shA[j * 260 + tid] = Kg[r * Dc + tid];
      }
      __syncthreads();
      float acc = 0.f;
      for (int d0 = 0; d0 < 256; d0 += 4) {
        float4 qv = *(const float4*)&shQ[xq * 260 + d0];
        float4 kv = *(const float4*)&shA[zl * 260 + d0];
        acc += qv.x * kv.x + qv.y * kv.y + qv.z * kv.z + qv.w * kv.w;
      }
      sc[zc] = acc;
    }
    // softmax over 64 z: 4 per lane x 16 lanes (xor shuffles stay in the 16-lane group)
    {
      float mx = fmaxf(fmaxf(sc[0], sc[1]), fmaxf(sc[2], sc[3]));
      #pragma unroll
      for (int off = 1; off < 16; off <<= 1) mx = fmaxf(mx, __shfl_xor(mx, off));
      float sum = 0.f;
      #pragma unroll
      for (int zc = 0; zc < 4; zc++) { sc[zc] = __expf(sc[zc] - mx); sum += sc[zc]; }
      #pragma unroll
      for (int off = 1; off < 16; off <<= 1) sum += __shfl_xor(sum, off);
      float inv = 1.f / sum;
      #pragma unroll
      for (int zc = 0; zc < 4; zc++) shS[xq * 68 + zc * 16 + zl] = sc[zc] * inv;
    }
    __syncthreads();                               // S4: probs visible
    // --- phase C: O = P @ V, then Z-scale by os[h][d] (spec: diagonal d, sum v) ---
    {
      float oacc[QR];
      #pragma unroll
      for (int i = 0; i < QR; i++) oacc[i] = 0.f;
      for (int z = 0; z < 64; z += 2) {
        size_t r0v = mode ? ((size_t)(b * 64 + slice) * 64 + z)
                          : ((size_t)(b * 64 + z) * 64 + slice);
        size_t r1v = mode ? (r0v + 1) : (r0v + 64);
        float v0 = bf2f(Vg[r0v * Dc + tid]);
        float v1 = bf2f(Vg[r1v * Dc + tid]);
        #pragma unroll
        for (int i = 0; i < QR; i++) {
          float2 p2 = *(const float2*)&shS[i * 68 + z];
          oacc[i] += p2.x * v0 + p2.y * v1;
        }
      }
      #pragma unroll
      for (int i = 0; i < QR; i++) zacc[i] += oacc[i] * os_h;
    }
  }
  // --- write Z in TOKEN space (un-permute folded in); mode0 '=', mode1 '+=' ---
  #pragma unroll
  for (int i = 0; i < QR; i++) {
    int m = mode ? slice : (x0 + i);
    int n = mode ? (x0 + i) : slice;
    int himg = (n >> 3) * 8 + (m >> 3);
    int wimg = (n & 7) * 8 + (m & 7);
    size_t zi = ((size_t)(b * 4096 + himg * 64 + wimg)) * Dc + tid;
    if (mode) Z[zi] = f2bf(bf2f(Z[zi]) + zacc[i]);
    else      Z[zi] = f2bf(zacc[i]);
  }
}

// ---------------- residual + LN2 (Z token-space); x2 -> d_out fp32, h -> bf16 ----------------
__global__ __launch_bounds__(256) void ln2_kernel(
    const float* __restrict__ x, const ushort_t* __restrict__ Z,
    const float* __restrict__ w, const float* __restrict__ bia,
    float* __restrict__ x2out, ushort_t* __restrict__ h_bf) {
  int row = blockIdx.x;
  int d   = threadIdx.x;
  size_t rd = (size_t)row * Dc + d;
  float v = x[rd] + bf2f(Z[rd]);
  float s = v, sq = v * v;
  #pragma unroll
  for (int off = 32; off; off >>= 1) { s += __shfl_xor(s, off); sq += __shfl_xor(sq, off); }
  __shared__ float ps[4], pq[4];
  int wid = d >> 6, lane = d & 63;
  if (lane == 0) { ps[wid] = s; pq[wid] = sq; }
  __syncthreads();
  s  = ps[0] + ps[1] + ps[2] + ps[3];
  sq = pq[0] + pq[1] + pq[2] + pq[3];
  float mean = s * (1.f / Dc);
  float var  = sq * (1.f / Dc) - mean * mean;
  float r    = rsqrtf(var + EPSc);
  x2out[rd] = v;
  h_bf[rd]  = f2bf((v - mean) * r * w[d] + bia[d]);
}

extern "C" void kernel_launch(void* const* d_in, const int* in_sizes, int n_in,
                              void* d_out, int out_size, void* d_ws, size_t ws_size,
                              hipStream_t stream) {
  const float* x    = (const float*)d_in[0];
  const float* ln1w = (const float*)d_in[1];
  const float* ln1b = (const float*)d_in[2];
  const float* q    = (const float*)d_in[3];
  const float* k    = (const float*)d_in[4];
  const float* v    = (const float*)d_in[5];
  const float* o    = (const float*)d_in[6];
  const float* ln2w = (const float*)d_in[7];
  const float* ln2b = (const float*)d_in[8];
  const float* w1   = (const float*)d_in[9];
  const float* b1   = (const float*)d_in[10];
  const float* w2   = (const float*)d_in[11];
  const float* b2   = (const float*)d_in[12];
  float* out = (float*)d_out;

  const size_t ROWS = (size_t)Bc * Tc;   // 32768
  const size_t ELTS = ROWS * Dc;         // 8,388,608
  // ws plan (r1's behavior proves ws_size >= 112M; we use ~64M):
  //   [0 : 8K)          os[h][d] = sum_v o[h,d,v]
  //   [8K : 32M+8K)     a fp32 (blocked)  -> after attn: h_bf [8K:16M+8K), t_bf [16M+8K:32M+8K)
  //   [32M+8K : 48M+8K) Z bf16 (token space, accumulated across the two attn launches)
  //   [48M+8K : 64M+8K) V bf16 (blocked)
  // d_out: K fp32 (blocked) during attention; overwritten by LN2's fp32 x2 afterwards.
  char* ws = (char*)d_ws;
  float*    osum = (float*)ws;
  float*    aF   = (float*)(ws + 8192);
  ushort_t* Z_bf = (ushort_t*)(ws + 8192 + ELTS * sizeof(float));
  ushort_t* V_bf = (ushort_t*)(ws + 8192 + ELTS * sizeof(float) + ELTS * sizeof(ushort_t));
  float*    K_f  = (float*)d_out;
  ushort_t* h_bf = (ushort_t*)(ws + 8192);
  ushort_t* t_bf = (ushort_t*)(ws + 8192 + ELTS * sizeof(ushort_t));

  // 0. os = row-sums of o (the spec's 'hdv->...d' diagonal/sum einsum)
  osum_kernel<<<8, 256, 0, stream>>>(o, osum);
  // 1. LN1 + permute -> fp32 a
  ln1_kernel<<<ROWS, 256, 0, stream>>>(x, ln1w, ln1b, aF);
  // 2. K (fp32, score chain) and V (bf16) projections
  mm_f32_kernel<<<ROWS / 32, 256, 0, stream>>>(aF, k, K_f, nullptr);
  mm_f32_kernel<<<ROWS / 32, 256, 0, stream>>>(aF, v, nullptr, V_bf);
  // 3. attention: heads 0-3 (mode 0) '=', heads 4-7 (mode 1) '+='
  attn_kernel<<<2048, 256, 0, stream>>>(aF, K_f, V_bf, q, osum, Z_bf, 0);
  attn_kernel<<<2048, 256, 0, stream>>>(aF, K_f, V_bf, q, osum, Z_bf, 1);
  // 4. residual + LN2 (x2 -> d_out, h -> ws; a and K dead)
  ln2_kernel<<<ROWS, 256, 0, stream>>>(x, Z_bf, ln2w, ln2b, out, h_bf);
  // 5. MLP
  mm_bf_kernel<<<ROWS / 64, 256, 0, stream>>>(h_bf, w1, b1, nullptr, t_bf, nullptr, 1);
  mm_bf_kernel<<<ROWS / 64, 256, 0, stream>>>(t_bf, w2, b2, out, nullptr, out, 0);
}

// Round 6
// 764.227 us; speedup vs baseline: 2.9432x; 2.9432x over previous
//
#include <hip/hip_runtime.h>

// (B, N, D, H) = (8, 4096, 256, 8), PS=8 -> image 64x64; blocked m=fine pos, n=tile idx.
// SPEC FACT 1: no softmax temperature; logit sigma ~16. fp16 inputs + fp32 MFMA acc give
//   logit err ~0.01 (softmax-safe). bf16 would give ~0.045 (risky).
// SPEC FACT 2 (r4->r5): Z = einsum('bhmnd,hdv->bmnd', O, o) is DIAGONAL in d, SUMS v:
//   Z[...,d] = sum_h O_h[...,d] * os[h][d], os[h][d] = sum_v o[h,d,v].
// SPEC FACT 3: S = Q K^T = a (q[h] k^T) a^T = a M_h a^T. M_h precomputed fp32 -> f16.
// MFMA facts used (m89/m97/m120): mfma_f32_16x16x32_f16: C/D col=lane&15,row=(lane>>4)*4+reg;
//   A-op A[m=lane&15][k=(lane>>4)*8+j]; B-op row-major X[n][k] computes A @ X^T.
#define Bc   8
#define Tc   4096
#define Dc   256
#define EPSc 1e-5f

typedef _Float16 half_t;
typedef __attribute__((ext_vector_type(4))) _Float16 half4_t;
typedef __attribute__((ext_vector_type(8))) _Float16 frag8;
typedef __attribute__((ext_vector_type(4))) float f32x4;

#define MFMA_F16(a, b, c) __builtin_amdgcn_mfma_f32_16x16x32_f16((a), (b), (c), 0, 0, 0)

// ---------------- os[h][d] = sum_v o[h,d,v] (fp32) ----------------
__global__ __launch_bounds__(256) void osum_kernel(const float* __restrict__ o, float* __restrict__ os) {
  int h = blockIdx.x, d = threadIdx.x;
  const float* row = o + ((size_t)h * 256 + d) * 256;
  float s = 0.f;
  #pragma unroll 8
  for (int v = 0; v < 256; v += 4) {
    float4 r4 = *(const float4*)&row[v];
    s += r4.x + r4.y + r4.z + r4.w;
  }
  os[h * 256 + d] = s;
}

// ---------------- Mt[h][e][d] = M_h[d][e] = sum_i q[h][d][i]*k[e][i]  (f16 out) ----------------
__global__ __launch_bounds__(256) void prepM_kernel(const float* __restrict__ q,
                                                    const float* __restrict__ k,
                                                    half_t* __restrict__ Mt) {
  __shared__ float shK[64 * 256];   // 64 KB: k rows for this e-tile
  int h = blockIdx.x >> 2, et = blockIdx.x & 3;
  int tid = threadIdx.x;            // = d
  for (int i = 0; i < 64; i++) shK[i * 256 + tid] = k[(size_t)(et * 64 + i) * 256 + tid];
  __syncthreads();
  const float* qr = q + ((size_t)h * 256 + tid) * 256;   // q[h][d][:]
  float acc[64];
  #pragma unroll
  for (int e = 0; e < 64; e++) acc[e] = 0.f;
  for (int i0 = 0; i0 < 256; i0 += 4) {
    float4 qv = *(const float4*)&qr[i0];
    #pragma unroll
    for (int e = 0; e < 64; e++) {
      float4 kv = *(const float4*)&shK[e * 256 + i0];    // broadcast
      acc[e] += qv.x * kv.x + qv.y * kv.y + qv.z * kv.z + qv.w * kv.w;
    }
  }
  for (int e = 0; e < 64; e++)
    Mt[((size_t)h * 256 + et * 64 + e) * 256 + tid] = (half_t)acc[e];
}

// ---------------- transpose v/w1/w2 -> f16 [n][d] (B-operand format) ----------------
__global__ __launch_bounds__(256) void prepT_kernel(const float* __restrict__ v,
                                                    const float* __restrict__ w1,
                                                    const float* __restrict__ w2,
                                                    half_t* vt, half_t* w1t, half_t* w2t) {
  int which = blockIdx.x >> 8, n = blockIdx.x & 255, d = threadIdx.x;
  const float* src = which == 0 ? v : (which == 1 ? w1 : w2);
  half_t* dst = which == 0 ? vt : (which == 1 ? w1t : w2t);
  dst[(size_t)n * 256 + d] = (half_t)src[(size_t)d * 256 + n];
}

// ---------------- LN1 + blocked permute -> f16; one wave per row ----------------
__global__ __launch_bounds__(256) void ln1_kernel(
    const float* __restrict__ x, const float* __restrict__ w,
    const float* __restrict__ bia, half_t* __restrict__ aH) {
  int row  = blockIdx.x * 4 + (threadIdx.x >> 6);
  int lane = threadIdx.x & 63;
  float4 v = *(const float4*)&x[(size_t)row * 256 + lane * 4];
  float s  = v.x + v.y + v.z + v.w;
  float sq = v.x * v.x + v.y * v.y + v.z * v.z + v.w * v.w;
  #pragma unroll
  for (int off = 1; off < 64; off <<= 1) { s += __shfl_xor(s, off); sq += __shfl_xor(sq, off); }
  float mean = s * (1.f / 256), var = sq * (1.f / 256) - mean * mean;
  float r = rsqrtf(var + EPSc);
  float4 wv = *(const float4*)&w[lane * 4];
  float4 bv = *(const float4*)&bia[lane * 4];
  half4_t y;
  y[0] = (half_t)((v.x - mean) * r * wv.x + bv.x);
  y[1] = (half_t)((v.y - mean) * r * wv.y + bv.y);
  y[2] = (half_t)((v.z - mean) * r * wv.z + bv.z);
  y[3] = (half_t)((v.w - mean) * r * wv.w + bv.w);
  int bb = row >> 12, p = row & 4095, hh = p >> 6, ww = p & 63;
  int m = (hh & 7) * 8 + (ww & 7), n = (hh >> 3) * 8 + (ww >> 3);
  *(half4_t*)&aH[((size_t)((bb * 64 + m) * 64 + n)) * 256 + lane * 4] = y;
}

// ---------------- generic MFMA GEMM: 64 rows x 256 cols, K=256 ----------------
// epi 0: out f16 plain (V-proj). epi 1: +bias, relu -> f16 (fc1). epi 2: +bias +resid -> fp32 (fc2).
__global__ __launch_bounds__(256) void gemm_kernel(
    const half_t* __restrict__ A, const half_t* __restrict__ Bt,
    const float* __restrict__ bias, float* __restrict__ outf,
    half_t* __restrict__ outh, int epi) {
  __shared__ half_t shA[64 * 264];   // 33 KB, pad breaks 16-way conflicts (2-way = free)
  int tid = threadIdx.x, lane = tid & 63, wave = tid >> 6;
  int l16 = lane & 15, quad = lane >> 4;
  int r0 = blockIdx.x * 64;
  for (int it = 0; it < 16; it++) {
    int e = it * 1024 + tid * 4; int z = e >> 8, col = e & 255;
    *(half4_t*)&shA[z * 264 + col] = *(const half4_t*)&A[(size_t)(r0 + z) * 256 + col];
  }
  __syncthreads();
  f32x4 acc[4][4];
  #pragma unroll
  for (int mt = 0; mt < 4; mt++)
    #pragma unroll
    for (int nt = 0; nt < 4; nt++) acc[mt][nt] = (f32x4){0.f, 0.f, 0.f, 0.f};
  for (int ks = 0; ks < 8; ks++) {
    int k0 = ks * 32 + quad * 8;
    frag8 af[4], bf[4];
    #pragma unroll
    for (int mt = 0; mt < 4; mt++) af[mt] = *(const frag8*)&shA[(mt * 16 + l16) * 264 + k0];
    #pragma unroll
    for (int nt = 0; nt < 4; nt++) bf[nt] = *(const frag8*)&Bt[(size_t)(wave * 64 + nt * 16 + l16) * 256 + k0];
    #pragma unroll
    for (int mt = 0; mt < 4; mt++)
      #pragma unroll
      for (int nt = 0; nt < 4; nt++) acc[mt][nt] = MFMA_F16(af[mt], bf[nt], acc[mt][nt]);
  }
  #pragma unroll
  for (int mt = 0; mt < 4; mt++)
    #pragma unroll
    for (int nt = 0; nt < 4; nt++)
      #pragma unroll
      for (int r = 0; r < 4; r++) {
        int row = r0 + mt * 16 + quad * 4 + r;
        int col = wave * 64 + nt * 16 + l16;
        float vv = acc[mt][nt][r];
        if (epi) vv += bias[col];
        if (epi == 1) vv = fmaxf(vv, 0.f);
        size_t idx = (size_t)row * 256 + col;
        if (epi == 2) outf[idx] = vv + outf[idx];
        else          outh[idx] = (half_t)vv;
      }
}

// ---------------- K1: scores+softmax per mode. P[group][head][m][z] f16 ----------------
// mode 0 (heads 0-3): group fixed n=slice, tokens over m.  mode 1 (heads 4-7): fixed m=slice.
__global__ __launch_bounds__(256) void attn_score_kernel(
    const half_t* __restrict__ aH, const half_t* __restrict__ Mt,
    half_t* __restrict__ P, int mode) {
  __shared__ half_t shA[64 * 264];   // group's a rows (33 KB)
  __shared__ half_t shW[64 * 72];    // W e-chunk (9 KB)
  int tid = threadIdx.x, lane = tid & 63, wave = tid >> 6;
  int l16 = lane & 15, quad = lane >> 4;
  int b = blockIdx.x >> 6, slice = blockIdx.x & 63;
  for (int it = 0; it < 16; it++) {
    int e = it * 1024 + tid * 4; int z = e >> 8, col = e & 255;
    size_t rg = mode ? ((size_t)((b * 64 + slice) * 64 + z)) : ((size_t)((b * 64 + z) * 64 + slice));
    *(half4_t*)&shA[z * 264 + col] = *(const half4_t*)&aH[rg * 256 + col];
  }
  __syncthreads();
  int hbase = mode ? 4 : 0;
  for (int hh = 0; hh < 4; hh++) {
    const half_t* mth = Mt + (size_t)(hbase + hh) * 65536;
    f32x4 sacc[4];
    #pragma unroll
    for (int nt = 0; nt < 4; nt++) sacc[nt] = (f32x4){0.f, 0.f, 0.f, 0.f};
    for (int ec = 0; ec < 4; ec++) {
      // W chunk = A_g @ M[:, ec*64..+64): wave owns m-tile `wave`, 4 e-tiles
      f32x4 wacc[4];
      #pragma unroll
      for (int nt = 0; nt < 4; nt++) wacc[nt] = (f32x4){0.f, 0.f, 0.f, 0.f};
      for (int ks = 0; ks < 8; ks++) {
        int k0 = ks * 32 + quad * 8;
        frag8 af = *(const frag8*)&shA[(wave * 16 + l16) * 264 + k0];
        #pragma unroll
        for (int nt = 0; nt < 4; nt++) {
          frag8 bf = *(const frag8*)&mth[(size_t)(ec * 64 + nt * 16 + l16) * 256 + k0];
          wacc[nt] = MFMA_F16(af, bf, wacc[nt]);
        }
      }
      #pragma unroll
      for (int nt = 0; nt < 4; nt++)
        #pragma unroll
        for (int r = 0; r < 4; r++)
          shW[(wave * 16 + quad * 4 + r) * 72 + nt * 16 + l16] = (half_t)wacc[nt][r];
      __syncthreads();
      // S partial: S += W_chunk @ (A_g[:, e-chunk])^T
      #pragma unroll
      for (int ks = 0; ks < 2; ks++) {
        int k0 = ks * 32 + quad * 8;
        frag8 wf = *(const frag8*)&shW[(wave * 16 + l16) * 72 + k0];
        #pragma unroll
        for (int nt = 0; nt < 4; nt++) {
          frag8 kf = *(const frag8*)&shA[(nt * 16 + l16) * 264 + ec * 64 + k0];
          sacc[nt] = MFMA_F16(wf, kf, sacc[nt]);
        }
      }
      __syncthreads();   // before next chunk overwrites shW
    }
    // softmax: row = wave*16 + quad*4 + r; 64 cols live in 4 accs x 16 lanes of this quad
    size_t pb = ((size_t)blockIdx.x * 4 + hh) * 4096;
    #pragma unroll
    for (int r = 0; r < 4; r++) {
      float mx = fmaxf(fmaxf(sacc[0][r], sacc[1][r]), fmaxf(sacc[2][r], sacc[3][r]));
      #pragma unroll
      for (int off = 1; off < 16; off <<= 1) mx = fmaxf(mx, __shfl_xor(mx, off));
      float e0 = __expf(sacc[0][r] - mx), e1 = __expf(sacc[1][r] - mx);
      float e2 = __expf(sacc[2][r] - mx), e3 = __expf(sacc[3][r] - mx);
      float sum = e0 + e1 + e2 + e3;
      #pragma unroll
      for (int off = 1; off < 16; off <<= 1) sum += __shfl_xor(sum, off);
      float inv = 1.f / sum;
      size_t prow = pb + (size_t)(wave * 16 + quad * 4 + r) * 64 + l16;
      P[prow +  0] = (half_t)(e0 * inv);
      P[prow + 16] = (half_t)(e1 * inv);
      P[prow + 32] = (half_t)(e2 * inv);
      P[prow + 48] = (half_t)(e3 * inv);
    }
  }
}

// ---------------- K2: O = P@V, Z (+)= O * os[h], token-space store ----------------
__global__ __launch_bounds__(256) void attn_pv_kernel(
    const half_t* __restrict__ P, const half_t* __restrict__ VH,
    const float* __restrict__ osum, half_t* __restrict__ Z, int mode) {
  __shared__ half_t shV[256 * 72];   // V^T (36 KB), pad -> 2-way (free) on b128 reads
  int tid = threadIdx.x, lane = tid & 63, wave = tid >> 6;
  int l16 = lane & 15, quad = lane >> 4;
  int b = blockIdx.x >> 6, slice = blockIdx.x & 63;
  for (int it = 0; it < 16; it++) {
    int e = it * 1024 + tid * 4; int z = e >> 8, col = e & 255;
    size_t rg = mode ? ((size_t)((b * 64 + slice) * 64 + z)) : ((size_t)((b * 64 + z) * 64 + slice));
    half4_t vv = *(const half4_t*)&VH[rg * 256 + col];
    shV[(col + 0) * 72 + z] = vv[0];
    shV[(col + 1) * 72 + z] = vv[1];
    shV[(col + 2) * 72 + z] = vv[2];
    shV[(col + 3) * 72 + z] = vv[3];
  }
  __syncthreads();
  f32x4 zacc[16];
  #pragma unroll
  for (int dt = 0; dt < 16; dt++) zacc[dt] = (f32x4){0.f, 0.f, 0.f, 0.f};
  int hbase = mode ? 4 : 0;
  for (int hh = 0; hh < 4; hh++) {
    const half_t* ph = P + ((size_t)blockIdx.x * 4 + hh) * 4096;
    f32x4 oacc[16];
    #pragma unroll
    for (int dt = 0; dt < 16; dt++) oacc[dt] = (f32x4){0.f, 0.f, 0.f, 0.f};
    #pragma unroll
    for (int ks = 0; ks < 2; ks++) {
      int k0 = ks * 32 + quad * 8;
      frag8 pf = *(const frag8*)&ph[(size_t)(wave * 16 + l16) * 64 + k0];  // A-op, k-contiguous
      #pragma unroll
      for (int dt = 0; dt < 16; dt++) {
        frag8 vf = *(const frag8*)&shV[(dt * 16 + l16) * 72 + k0];
        oacc[dt] = MFMA_F16(pf, vf, oacc[dt]);
      }
    }
    #pragma unroll
    for (int dt = 0; dt < 16; dt++) {
      float osv = osum[(hbase + hh) * 256 + dt * 16 + l16];
      #pragma unroll
      for (int r = 0; r < 4; r++) zacc[dt][r] += oacc[dt][r] * osv;
    }
  }
  // store Z in token space (un-permute folded); mode0 '=', mode1 '+='
  for (int dt = 0; dt < 16; dt++) {
    int col = dt * 16 + l16;
    #pragma unroll
    for (int r = 0; r < 4; r++) {
      int grow = wave * 16 + quad * 4 + r;
      int m = mode ? slice : grow;
      int n = mode ? grow : slice;
      int himg = (n >> 3) * 8 + (m >> 3), wimg = (n & 7) * 8 + (m & 7);
      size_t zi = ((size_t)(b * 4096 + himg * 64 + wimg)) * 256 + col;
      if (mode) Z[zi] = (half_t)((float)Z[zi] + zacc[dt][r]);
      else      Z[zi] = (half_t)zacc[dt][r];
    }
  }
}

// ---------------- residual + LN2; x2 -> d_out fp32, h -> f16; one wave per row ----------------
__global__ __launch_bounds__(256) void ln2_kernel(
    const float* __restrict__ x, const half_t* __restrict__ Z,
    const float* __restrict__ w, const float* __restrict__ bia,
    float* __restrict__ x2out, half_t* __restrict__ hH) {
  int row  = blockIdx.x * 4 + (threadIdx.x >> 6);
  int lane = threadIdx.x & 63;
  size_t base = (size_t)row * 256 + lane * 4;
  float4 xv = *(const float4*)&x[base];
  half4_t zv = *(const half4_t*)&Z[base];
  float4 v;
  v.x = xv.x + (float)zv[0]; v.y = xv.y + (float)zv[1];
  v.z = xv.z + (float)zv[2]; v.w = xv.w + (float)zv[3];
  float s  = v.x + v.y + v.z + v.w;
  float sq = v.x * v.x + v.y * v.y + v.z * v.z + v.w * v.w;
  #pragma unroll
  for (int off = 1; off < 64; off <<= 1) { s += __shfl_xor(s, off); sq += __shfl_xor(sq, off); }
  float mean = s * (1.f / 256), var = sq * (1.f / 256) - mean * mean;
  float r = rsqrtf(var + EPSc);
  float4 wv = *(const float4*)&w[lane * 4];
  float4 bv = *(const float4*)&bia[lane * 4];
  *(float4*)&x2out[base] = v;
  half4_t y;
  y[0] = (half_t)((v.x - mean) * r * wv.x + bv.x);
  y[1] = (half_t)((v.y - mean) * r * wv.y + bv.y);
  y[2] = (half_t)((v.z - mean) * r * wv.z + bv.z);
  y[3] = (half_t)((v.w - mean) * r * wv.w + bv.w);
  *(half4_t*)&hH[base] = y;
}

extern "C" void kernel_launch(void* const* d_in, const int* in_sizes, int n_in,
                              void* d_out, int out_size, void* d_ws, size_t ws_size,
                              hipStream_t stream) {
  (void)in_sizes; (void)n_in; (void)out_size; (void)ws_size;
  const float* x    = (const float*)d_in[0];
  const float* ln1w = (const float*)d_in[1];
  const float* ln1b = (const float*)d_in[2];
  const float* q    = (const float*)d_in[3];
  const float* k    = (const float*)d_in[4];
  const float* v    = (const float*)d_in[5];
  const float* o    = (const float*)d_in[6];
  const float* ln2w = (const float*)d_in[7];
  const float* ln2b = (const float*)d_in[8];
  const float* w1   = (const float*)d_in[9];
  const float* b1   = (const float*)d_in[10];
  const float* w2   = (const float*)d_in[11];
  const float* b2   = (const float*)d_in[12];
  float* out = (float*)d_out;

  const size_t ROWS = (size_t)Bc * Tc;   // 32768
  const size_t ELTS = ROWS * Dc;         // 8,388,608
  const size_t MB16 = ELTS * sizeof(half_t);  // 16 MiB
  // ws plan (~66 MiB; ws >= 112 MiB established r1-r3):
  //   [0:8K)        os fp32
  //   [64K:1M+64K)  Mt f16 (8 heads, transposed [e][d])
  //   [+1M.. ]      vt / w1t / w2t f16 (128 KB each)
  //   [2M:18M)      aH f16 (blocked)   -> reused as hH after attention
  //   [18M:34M)     VH f16 (blocked)   -> reused as tH after attention
  //   [34M:50M)     Z f16 (token space)
  //   [50M:66M)     P f16 (per-mode scratch, reused across modes)
  char* ws = (char*)d_ws;
  float*  osumB = (float*)ws;
  half_t* Mt    = (half_t*)(ws + (64 << 10));
  half_t* vt    = (half_t*)(ws + (64 << 10) + (1 << 20));
  half_t* w1t   = (half_t*)(ws + (64 << 10) + (1 << 20) + (128 << 10));
  half_t* w2t   = (half_t*)(ws + (64 << 10) + (1 << 20) + (256 << 10));
  half_t* aH    = (half_t*)(ws + (2  << 20));
  half_t* VH    = (half_t*)(ws + (2  << 20) + MB16);
  half_t* Zb    = (half_t*)(ws + (2  << 20) + 2 * MB16);
  half_t* Pb    = (half_t*)(ws + (2  << 20) + 3 * MB16);
  half_t* hH    = aH;   // reuse (a dead after attention)
  half_t* tH    = VH;   // reuse (V dead after attention)

  osum_kernel <<<8,   256, 0, stream>>>(o, osumB);
  prepM_kernel<<<32,  256, 0, stream>>>(q, k, Mt);
  prepT_kernel<<<768, 256, 0, stream>>>(v, w1, w2, vt, w1t, w2t);
  ln1_kernel  <<<ROWS / 4, 256, 0, stream>>>(x, ln1w, ln1b, aH);
  // V projection (MFMA)
  gemm_kernel <<<ROWS / 64, 256, 0, stream>>>(aH, vt, nullptr, nullptr, VH, 0);
  // attention: scores+softmax then PV, per mode (mode0 '=', mode1 '+=')
  attn_score_kernel<<<512, 256, 0, stream>>>(aH, Mt, Pb, 0);
  attn_pv_kernel   <<<512, 256, 0, stream>>>(Pb, VH, osumB, Zb, 0);
  attn_score_kernel<<<512, 256, 0, stream>>>(aH, Mt, Pb, 1);
  attn_pv_kernel   <<<512, 256, 0, stream>>>(Pb, VH, osumB, Zb, 1);
  // residual + LN2
  ln2_kernel  <<<ROWS / 4, 256, 0, stream>>>(x, Zb, ln2w, ln2b, out, hH);
  // MLP (MFMA): fc1 relu -> tH; fc2 + bias + resid -> out fp32
  gemm_kernel <<<ROWS / 64, 256, 0, stream>>>(hH, w1t, b1, nullptr, tH, 1);
  gemm_kernel <<<ROWS / 64, 256, 0, stream>>>(tH, w2t, b2, out, nullptr, 2);
}